// Round 14
// baseline (846.185 us; speedup 1.0000x reference)
//
#include <hip/hip_runtime.h>
#include <stdint.h>

#define OBS 64
#define ACTD 16
#define DIN 80          // OBS+ACT
#define MIX 16
#define FF 4096         // HID*MIX
#define NB 16384        // batch
#define CHUNK 4096      // rows per pipeline chunk
#define KP 96           // padded K for GEMM1 (80 + bias col + zeros)
#define LNEPS 1e-5f

typedef float f32x4 __attribute__((ext_vector_type(4)));
typedef short bf16x8 __attribute__((ext_vector_type(8)));

__device__ __forceinline__ unsigned short f2bf(float f) {
    union { float f; uint32_t u; } v; v.f = f;
    uint32_t u = v.u;
    u += 0x7fff + ((u >> 16) & 1);          // RNE
    return (unsigned short)(u >> 16);
}
__device__ __forceinline__ float bf2f(unsigned short h) {
    union { uint32_t u; float f; } v; v.u = ((uint32_t)h) << 16;
    return v.f;
}

// ---------------------------------------------------------------- W2 -> bf16
__global__ __launch_bounds__(256) void k_conv(const float* __restrict__ W,
                                              unsigned short* __restrict__ O, int n4) {
    int i = blockIdx.x * 256 + threadIdx.x;
    if (i >= n4) return;
    float4 v = ((const float4*)W)[i];
    ushort4 o;
    o.x = f2bf(v.x); o.y = f2bf(v.y); o.z = f2bf(v.z); o.w = f2bf(v.w);
    ((ushort4*)O)[i] = o;
}

// ------------- fused prep: blocks 0-15 -> xab rows; blocks 16-31 -> W1b rows
__global__ __launch_bounds__(256) void k_prep(const float* __restrict__ x, const float* __restrict__ a,
                                              const float* __restrict__ W1, const float* __restrict__ b1,
                                              unsigned short* __restrict__ xab,
                                              unsigned short* __restrict__ W1b) {
    int t = threadIdx.x;
    if (blockIdx.x < 16) {
        int row = blockIdx.x * 256 + t;
        const float4* xp = (const float4*)(x + (size_t)row * OBS);
        unsigned short* o = xab + (size_t)row * KP;
#pragma unroll
        for (int i = 0; i < 16; ++i) {
            float4 v = xp[i];
            ushort4 u; u.x = f2bf(v.x); u.y = f2bf(v.y); u.z = f2bf(v.z); u.w = f2bf(v.w);
            ((ushort4*)o)[i] = u;
        }
        const float4* ap = (const float4*)(a + (size_t)row * ACTD);
#pragma unroll
        for (int i = 0; i < 4; ++i) {
            float4 v = ap[i];
            ushort4 u; u.x = f2bf(v.x); u.y = f2bf(v.y); u.z = f2bf(v.z); u.w = f2bf(v.w);
            ((ushort4*)(o + OBS))[i] = u;
        }
        ushort4 t0; t0.x = 0x3F80; t0.y = 0; t0.z = 0; t0.w = 0;   // 1.0bf16
        ushort4 z;  z.x = 0; z.y = 0; z.z = 0; z.w = 0;
        ((ushort4*)(o + 80))[0] = t0;
        ((ushort4*)(o + 84))[0] = z;
        ((ushort4*)(o + 88))[0] = z;
        ((ushort4*)(o + 92))[0] = z;
    } else {
        int f = (blockIdx.x - 16) * 256 + t;
        const float4* wp = (const float4*)(W1 + (size_t)f * DIN);
        unsigned short* o = W1b + (size_t)f * KP;
#pragma unroll
        for (int i = 0; i < 20; ++i) {
            float4 v = wp[i];
            ushort4 u; u.x = f2bf(v.x); u.y = f2bf(v.y); u.z = f2bf(v.z); u.w = f2bf(v.w);
            ((ushort4*)o)[i] = u;
        }
        ushort4 t0; t0.x = f2bf(b1[f]); t0.y = 0; t0.z = 0; t0.w = 0;
        ushort4 z;  z.x = 0; z.y = 0; z.z = 0; z.w = 0;
        ((ushort4*)(o + 80))[0] = t0;
        ((ushort4*)(o + 84))[0] = z;
        ((ushort4*)(o + 88))[0] = z;
        ((ushort4*)(o + 92))[0] = z;
    }
}

// ------------------------------------------------- gating (fp64) + top4 + renorm
__global__ __launch_bounds__(256) void k_gate(const float* __restrict__ x, const float* __restrict__ a,
                                              const float* __restrict__ Wg, const float* __restrict__ bg,
                                              float* __restrict__ scores) {
    __shared__ float wgs[MIX * DIN];
    __shared__ float bgs[MIX];
    int t = threadIdx.x;
    for (int e = t; e < MIX * DIN; e += 256) wgs[e] = Wg[e];
    if (t < MIX) bgs[t] = bg[t];
    __syncthreads();
    int row = blockIdx.x * 256 + t;
    float xa[DIN];
    const float4* xp = (const float4*)(x + (size_t)row * OBS);
#pragma unroll
    for (int i = 0; i < OBS / 4; ++i) {
        float4 v = xp[i];
        xa[i*4] = v.x; xa[i*4+1] = v.y; xa[i*4+2] = v.z; xa[i*4+3] = v.w;
    }
    const float4* ap = (const float4*)(a + (size_t)row * ACTD);
#pragma unroll
    for (int i = 0; i < ACTD / 4; ++i) {
        float4 v = ap[i];
        xa[OBS+i*4] = v.x; xa[OBS+i*4+1] = v.y; xa[OBS+i*4+2] = v.z; xa[OBS+i*4+3] = v.w;
    }
    double p[MIX];
    double mx = -1e300;
#pragma unroll
    for (int m = 0; m < MIX; ++m) {
        double acc = (double)bgs[m];
#pragma unroll
        for (int k = 0; k < DIN; ++k) acc += (double)xa[k] * (double)wgs[m*DIN + k];
        p[m] = acc;
        if (acc > mx) mx = acc;
    }
#pragma unroll
    for (int m = 0; m < MIX; ++m) p[m] = exp(p[m] - mx);
    unsigned used = 0;
    double s4 = 0.0;
#pragma unroll
    for (int j = 0; j < 4; ++j) {
        int best = 0; double bv = -1.0;
#pragma unroll
        for (int m = 0; m < MIX; ++m)
            if (!((used >> m) & 1) && p[m] > bv) { bv = p[m]; best = m; }
        used |= 1u << best;
        s4 += bv;
    }
    float* so = scores + (size_t)row * MIX;
#pragma unroll
    for (int m = 0; m < MIX; ++m)
        so[m] = ((used >> m) & 1) ? (float)(p[m] / s4) : 0.f;
}

// ---------------- GEMM1 (bf16 MFMA): h1 = xab @ W1b^T, pre-LN bf16 + partial stats
__global__ __launch_bounds__(256) void k_gemm1(const unsigned short* __restrict__ A,
                                               const unsigned short* __restrict__ B,
                                               unsigned short* __restrict__ C,
                                               float* __restrict__ pstats) {
    __shared__ alignas(16) unsigned short As[12288];   // 128 x 96
    __shared__ alignas(16) unsigned short Bs[12288];
    int t = threadIdx.x;
    int pm = blockIdx.x & 31;        // 32 M tiles (CHUNK/128)
    int pn = blockIdx.x >> 5;        // 32 N tiles
    int lane = t & 63, wid = t >> 6, wm = wid >> 1, wn = wid & 1;
    int l15 = lane & 15, l4 = lane >> 4;

    const unsigned short* Ap = A + (size_t)pm * 128 * KP;
    const unsigned short* Bp = B + (size_t)pn * 128 * KP;

#pragma unroll
    for (int i = 0; i < 6; ++i) {
        int u = i * 256 + t;
        int r = u / 12, s12 = u - r * 12;
        int q = s12 >> 2, s = s12 & 3;
        int goff = r * KP + q * 32 + ((s ^ ((r >> 1) & 3)) * 8);   // pre-swizzled source
        __builtin_amdgcn_global_load_lds(
            (const __attribute__((address_space(1))) void*)(Ap + goff),
            (__attribute__((address_space(3))) void*)(As + u * 8), 16, 0, 0);
        __builtin_amdgcn_global_load_lds(
            (const __attribute__((address_space(1))) void*)(Bp + goff),
            (__attribute__((address_space(3))) void*)(Bs + u * 8), 16, 0, 0);
    }
    __syncthreads();

    f32x4 acc[4][4] = {};
#pragma unroll
    for (int q = 0; q < 3; ++q) {
        bf16x8 af[4], bfr[4];
#pragma unroll
        for (int mf = 0; mf < 4; ++mf) {
            int r = wm * 64 + mf * 16 + l15;
            int sl = l4 ^ ((r >> 1) & 3);
            af[mf] = *(const bf16x8*)(As + (r * 12 + q * 4 + sl) * 8);
        }
#pragma unroll
        for (int nf = 0; nf < 4; ++nf) {
            int r = wn * 64 + nf * 16 + l15;
            int sl = l4 ^ ((r >> 1) & 3);
            bfr[nf] = *(const bf16x8*)(Bs + (r * 12 + q * 4 + sl) * 8);
        }
#pragma unroll
        for (int mf = 0; mf < 4; ++mf)
#pragma unroll
            for (int nf = 0; nf < 4; ++nf)
                acc[mf][nf] = __builtin_amdgcn_mfma_f32_16x16x32_bf16(af[mf], bfr[nf], acc[mf][nf], 0, 0, 0);
    }

    int rowbase = pm * 128 + wm * 64 + l4 * 4;
#pragma unroll
    for (int mf = 0; mf < 4; ++mf) {
#pragma unroll
        for (int rr = 0; rr < 4; ++rr) {
            float ss = 0.f, qq = 0.f;
#pragma unroll
            for (int nf = 0; nf < 4; ++nf) {
                float v = acc[mf][nf][rr];
                ss += v; qq += v * v;
            }
#pragma unroll
            for (int mask = 1; mask <= 8; mask <<= 1) {
                ss += __shfl_xor(ss, mask);
                qq += __shfl_xor(qq, mask);
            }
            if (l15 == 0) {
                int row = rowbase + mf * 16 + rr;
                int j = pn * 2 + wn;
                pstats[((size_t)row * 64 + j) * 2 + 0] = ss;
                pstats[((size_t)row * 64 + j) * 2 + 1] = qq;
            }
        }
    }

    __syncthreads();
    unsigned short* tw = As + wid * 1280;   // 16 rows x 64 cols, stride 80 shorts
#pragma unroll
    for (int mf = 0; mf < 4; ++mf) {
#pragma unroll
        for (int nf = 0; nf < 4; ++nf)
#pragma unroll
            for (int rr = 0; rr < 4; ++rr) {
                int row16 = l4 * 4 + rr;
                int col = l15 + nf * 16;
                tw[row16 * 80 + col] = f2bf(acc[mf][nf][rr]);
            }
        asm volatile("s_waitcnt lgkmcnt(0)" ::: "memory");
        const bf16x8* rp = (const bf16x8*)(tw + (lane >> 2) * 80 + (lane & 3) * 16);
        bf16x8 v0 = rp[0];
        bf16x8 v1 = rp[1];
        int grow = pm * 128 + wm * 64 + mf * 16 + (lane >> 2);
        int gcol = pn * 128 + wn * 64 + (lane & 3) * 16;
        *(bf16x8*)(C + (size_t)grow * FF + gcol) = v0;
        *(bf16x8*)(C + (size_t)grow * FF + gcol + 8) = v1;
        asm volatile("s_waitcnt lgkmcnt(0)" ::: "memory");
    }
}

// ---------------- LN1 finalize: reduce 64 partials/row, normalize+ReLU h1 in place
__global__ __launch_bounds__(256) void k_ln1(unsigned short* __restrict__ h1,
                                             const float* __restrict__ pstats,
                                             const float* __restrict__ g1, const float* __restrict__ be1) {
    __shared__ float st[8][2];
    int t = threadIdx.x;
    int r0 = blockIdx.x * 8;
    if (t < 8) {
        float s = 0.f, q = 0.f;
        const float* pp = pstats + (size_t)(r0 + t) * 128;
#pragma unroll
        for (int j = 0; j < 64; ++j) { s += pp[j * 2]; q += pp[j * 2 + 1]; }
        float mu = s / (float)FF;
        float var = q / (float)FF - mu * mu;
        st[t][0] = mu;
        st[t][1] = rsqrtf(var + LNEPS);
    }
    __syncthreads();
    int c = t * 16;
    float g[16], b[16];
#pragma unroll
    for (int q = 0; q < 4; ++q) {
        float4 gv = *(const float4*)(g1 + c + q * 4);
        float4 bv = *(const float4*)(be1 + c + q * 4);
        g[q*4] = gv.x; g[q*4+1] = gv.y; g[q*4+2] = gv.z; g[q*4+3] = gv.w;
        b[q*4] = bv.x; b[q*4+1] = bv.y; b[q*4+2] = bv.z; b[q*4+3] = bv.w;
    }
    for (int r = 0; r < 8; ++r) {
        float mu = st[r][0], rs = st[r][1];
        unsigned short* hp = h1 + (size_t)(r0 + r) * FF + c;
        uint4 u0 = *(const uint4*)hp;
        uint4 u1 = *(const uint4*)(hp + 8);
        uint32_t uu[8] = {u0.x, u0.y, u0.z, u0.w, u1.x, u1.y, u1.z, u1.w};
        uint32_t oo[8];
#pragma unroll
        for (int q = 0; q < 8; ++q) {
            float v0 = bf2f((unsigned short)(uu[q] & 0xffff));
            float v1 = bf2f((unsigned short)(uu[q] >> 16));
            float o0 = fmaxf((v0 - mu) * rs * g[q*2]   + b[q*2],   0.f);
            float o1 = fmaxf((v1 - mu) * rs * g[q*2+1] + b[q*2+1], 0.f);
            oo[q] = (uint32_t)f2bf(o0) | ((uint32_t)f2bf(o1) << 16);
        }
        uint4 w0; w0.x = oo[0]; w0.y = oo[1]; w0.z = oo[2]; w0.w = oo[3];
        uint4 w1; w1.x = oo[4]; w1.y = oo[5]; w1.z = oo[6]; w1.w = oo[7];
        *(uint4*)hp = w0;
        *(uint4*)(hp + 8) = w1;
    }
}

// ------------- GEMM2: y2 = h1 @ W2^T  (bf16 MFMA, 128x256 tile, BK=32, 2 blocks/CU)
// Occupancy play: acc 64 regs/lane -> 4 waves/SIMD; LDS 48KB. R10 sync discipline:
// counted vmcnt(1) at tile top (never 0 in loop), stages spread, hoisted pointers.
// Swizzle (BK=32): slot sl = l4 ^ ((row>>1)&3); pre-swizzled source, linear dest.
__global__ __launch_bounds__(512, 4) void k_gemm2(const unsigned short* __restrict__ A,
                                                  const unsigned short* __restrict__ B,
                                                  unsigned short* __restrict__ C) {
    constexpr int K = FF;                // 4096
    constexpr int NKT = K / 32;          // 128 K-tiles
    __shared__ alignas(16) unsigned short As[2][4096];   // [buf][128 rows x 32]
    __shared__ alignas(16) unsigned short Bs[2][8192];   // [buf][256 rows x 32]

    int t = threadIdx.x;
    int lane = t & 63, wid = t >> 6;
    int wm = wid >> 2, wn = wid & 3;     // 2 M-halves x 4 N-quarters; 64x64 per wave

    // bijective XCD swizzle: 32x16 tile grid, 512 blocks, 8 rects of 8x8
    int bid = blockIdx.x;
    int xcd = bid & 7, w = bid >> 3;
    int pm = (xcd >> 1) * 8 + (w >> 3);  // [0,32)
    int pn = (xcd & 1) * 8 + (w & 7);    // [0,16)

    const unsigned short* Ap = A + (size_t)pm * 128 * K;
    const unsigned short* Bp = B + (size_t)pn * 256 * K;

    int l15 = lane & 15, l4 = lane >> 4;
    int slk = (l4 ^ ((l15 >> 1) & 3)) * 16;    // byte slot; row-invariant (row deltas ≡0 mod 8... mod 4 of >>1)
    const char* afp = (const char*)&As[0][0] + wm * 4096 + l15 * 64 + slk;  // +m*1024, +buf*8192
    const char* bfp = (const char*)&Bs[0][0] + wn * 4096 + l15 * 64 + slk;  // +n*1024, +buf*16384

    int r0 = t >> 2;
    int swz = ((t & 3) ^ ((r0 >> 1) & 3)) * 8;  // elems; constant across tiles
    const unsigned short* sA  = Ap + (size_t)r0 * K + swz;
    const unsigned short* sB0 = Bp + (size_t)r0 * K + swz;
    const unsigned short* sB1 = Bp + (size_t)(128 + r0) * K + swz;
    char* dA = (char*)&As[0][0] + t * 16;
    char* dB = (char*)&Bs[0][0] + t * 16;

    f32x4 acc[4][4] = {};
    bf16x8 af[4], bfr[4];

#define STG_A2(BUF)                                                                         \
    __builtin_amdgcn_global_load_lds((const __attribute__((address_space(1))) void*)(sA),   \
        (__attribute__((address_space(3))) void*)(dA + (BUF)*8192), 16, 0, 0);
#define STG_B2(BUF, H)                                                                      \
    __builtin_amdgcn_global_load_lds(                                                       \
        (const __attribute__((address_space(1))) void*)((H) ? sB1 : sB0),                   \
        (__attribute__((address_space(3))) void*)(dB + (BUF)*16384 + (H)*8192), 16, 0, 0);

#define RD_AF2(BUF)                                                                         \
    _Pragma("unroll") for (int m = 0; m < 4; ++m)                                           \
        af[m] = *(const bf16x8*)(afp + (BUF)*8192 + m*1024);
#define RD_BF2(BUF, NLO)                                                                    \
    _Pragma("unroll") for (int n2 = 0; n2 < 2; ++n2)                                        \
        bfr[(NLO) + n2] = *(const bf16x8*)(bfp + (BUF)*16384 + ((NLO) + n2)*1024);

#define MFMA_Q8(NLO)                                                                        \
    __builtin_amdgcn_s_setprio(1);                                                          \
    _Pragma("unroll") for (int m = 0; m < 4; ++m)                                           \
    _Pragma("unroll") for (int n = (NLO); n < (NLO) + 2; ++n)                               \
        acc[m][n] = __builtin_amdgcn_mfma_f32_16x16x32_bf16(af[m], bfr[n], acc[m][n], 0, 0, 0); \
    __builtin_amdgcn_s_setprio(0);                                                          \
    __builtin_amdgcn_sched_barrier(0);

#define TILE2(BUF, DO_STAGE)                                                                \
    if (DO_STAGE) { STG_A2(1 - (BUF)) }                                                     \
    if (DO_STAGE) asm volatile("s_waitcnt vmcnt(1)" ::: "memory");                          \
    else          asm volatile("s_waitcnt vmcnt(0)" ::: "memory");                          \
    __builtin_amdgcn_s_barrier();                                                           \
    __builtin_amdgcn_sched_barrier(0);                                                      \
    RD_AF2(BUF) RD_BF2(BUF, 0)                                                              \
    MFMA_Q8(0)                                                                              \
    if (DO_STAGE) { STG_B2(1 - (BUF), 0) }                                                  \
    RD_BF2(BUF, 2)                                                                          \
    MFMA_Q8(2)                                                                              \
    if (DO_STAGE) { STG_B2(1 - (BUF), 1) }                                                  \
    asm volatile("" ::: "memory");                                                          \
    __builtin_amdgcn_s_barrier();                                                           \
    asm volatile("" ::: "memory");                                                          \
    if (DO_STAGE) { sA += 32; sB0 += 32; sB1 += 32; }

    // prologue: stage tile 0 (3 loads), advance to tile 1
    STG_A2(0) STG_B2(0, 0) STG_B2(0, 1)
    sA += 32; sB0 += 32; sB1 += 32;
    asm volatile("" ::: "memory");

    for (int i = 0; i < NKT / 2 - 1; ++i) {
        TILE2(0, true)
        TILE2(1, true)
    }
    TILE2(0, true)       // tile 126 (stages tile 127)
    TILE2(1, false)      // tile 127 (no stages; vmcnt(0))

#undef STG_A2
#undef STG_B2
#undef RD_AF2
#undef RD_BF2
#undef MFMA_Q8
#undef TILE2

    int row0 = pm * 128 + wm * 64 + l4 * 4;
    int col0 = pn * 256 + wn * 64 + l15;
#pragma unroll
    for (int m = 0; m < 4; ++m)
#pragma unroll
        for (int n = 0; n < 4; ++n)
#pragma unroll
            for (int j = 0; j < 4; ++j)
                C[(size_t)(row0 + m * 16 + j) * FF + col0 + n * 16] = f2bf(acc[m][n][j]);
}

// ------------------- fused +b2, LN2, ReLU, score mixture, x W3 + b3 -> out[row]
__global__ __launch_bounds__(256) void k_epi(const unsigned short* __restrict__ y2,
                                             const float* __restrict__ scores,
                                             const float* __restrict__ b2,
                                             const float* __restrict__ g2, const float* __restrict__ be2,
                                             const float* __restrict__ W3, const float* __restrict__ b3,
                                             float* __restrict__ out) {
    int row = blockIdx.x, t = threadIdx.x;
    int lane = t & 63, wid = t >> 6;
    __shared__ float sS[MIX];
    __shared__ float rA[4], rB[4];
    __shared__ float stats[2];
    const unsigned short* yp = y2 + (size_t)row * FF + t * 16;
    uint4 u0 = *(const uint4*)yp;
    uint4 u1 = *(const uint4*)(yp + 8);
    float v[16];
    v[0]  = bf2f((unsigned short)(u0.x & 0xffff)); v[1]  = bf2f((unsigned short)(u0.x >> 16));
    v[2]  = bf2f((unsigned short)(u0.y & 0xffff)); v[3]  = bf2f((unsigned short)(u0.y >> 16));
    v[4]  = bf2f((unsigned short)(u0.z & 0xffff)); v[5]  = bf2f((unsigned short)(u0.z >> 16));
    v[6]  = bf2f((unsigned short)(u0.w & 0xffff)); v[7]  = bf2f((unsigned short)(u0.w >> 16));
    v[8]  = bf2f((unsigned short)(u1.x & 0xffff)); v[9]  = bf2f((unsigned short)(u1.x >> 16));
    v[10] = bf2f((unsigned short)(u1.y & 0xffff)); v[11] = bf2f((unsigned short)(u1.y >> 16));
    v[12] = bf2f((unsigned short)(u1.z & 0xffff)); v[13] = bf2f((unsigned short)(u1.z >> 16));
    v[14] = bf2f((unsigned short)(u1.w & 0xffff)); v[15] = bf2f((unsigned short)(u1.w >> 16));
    const float* b2p = b2 + t * 16;
#pragma unroll
    for (int blk = 0; blk < 4; ++blk) {
        float4 q = *(const float4*)(b2p + blk * 4);
        v[blk*4+0] += q.x; v[blk*4+1] += q.y; v[blk*4+2] += q.z; v[blk*4+3] += q.w;
    }
    if (t < MIX) sS[t] = scores[(size_t)row * MIX + t];
    float s = 0.f, sq = 0.f;
#pragma unroll
    for (int j = 0; j < 16; ++j) { s += v[j]; sq += v[j] * v[j]; }
#pragma unroll
    for (int off = 32; off >= 1; off >>= 1) {
        s  += __shfl_down(s, off);
        sq += __shfl_down(sq, off);
    }
    if (lane == 0) { rA[wid] = s; rB[wid] = sq; }
    __syncthreads();
    if (t == 0) {
        float S = rA[0] + rA[1] + rA[2] + rA[3];
        float Q = rB[0] + rB[1] + rB[2] + rB[3];
        float mu = S / (float)FF;
        float var = Q / (float)FF - mu * mu;
        stats[0] = mu;
        stats[1] = rsqrtf(var + LNEPS);
    }
    __syncthreads();
    float mu = stats[0], rs = stats[1];
    const float* gp = g2 + t * 16;
    const float* bp = be2 + t * 16;
    float accum = 0.f;
#pragma unroll
    for (int blk = 0; blk < 4; ++blk) {
        float4 gg = *(const float4*)(gp + blk * 4);
        float4 bb = *(const float4*)(bp + blk * 4);
        float ga[4] = {gg.x, gg.y, gg.z, gg.w};
        float ba[4] = {bb.x, bb.y, bb.z, bb.w};
#pragma unroll
        for (int jj = 0; jj < 4; ++jj) {
            int m = blk * 4 + jj;
            float o = (v[m] - mu) * rs * ga[jj] + ba[jj];
            o = fmaxf(o, 0.f);
            accum += o * sS[m];
        }
    }
    float part = accum * W3[t] * 0.0625f;   // /16 (mean over MIX)
#pragma unroll
    for (int off = 32; off >= 1; off >>= 1) part += __shfl_down(part, off);
    if (lane == 0) rA[wid] = part;
    __syncthreads();
    if (t == 0) out[row] = rA[0] + rA[1] + rA[2] + rA[3] + b3[0];
}

extern "C" void kernel_launch(void* const* d_in, const int* in_sizes, int n_in,
                              void* d_out, int out_size, void* d_ws, size_t ws_size,
                              hipStream_t stream) {
    const float* x   = (const float*)d_in[0];
    const float* a   = (const float*)d_in[1];
    const float* W1  = (const float*)d_in[2];
    const float* b1  = (const float*)d_in[3];
    const float* W2  = (const float*)d_in[4];
    const float* b2  = (const float*)d_in[5];
    const float* W3  = (const float*)d_in[6];
    const float* b3  = (const float*)d_in[7];
    const float* g1  = (const float*)d_in[8];
    const float* be1 = (const float*)d_in[9];
    const float* g2  = (const float*)d_in[10];
    const float* be2 = (const float*)d_in[11];
    const float* Wg  = (const float*)d_in[12];
    const float* bg  = (const float*)d_in[13];
    float* out = (float*)d_out;

    // workspace layout — total 101,711,872 B (R2-proven-safe footprint).
    char* ws = (char*)d_ws;
    unsigned short* W2b    = (unsigned short*)ws;                    // 32 MB
    float*          scores = (float*)(ws + 33554432ull);            // 1 MB
    unsigned short* h1c    = (unsigned short*)(ws + 34603008ull);    // 32 MB
    unsigned short* y2c    = (unsigned short*)(ws + 68157440ull);    // 32 MB (+scratch head)
    unsigned short* xabc   = (unsigned short*)(ws + 68157440ull);            // 768 KB
    unsigned short* W1b    = (unsigned short*)(ws + 68157440ull + 786432ull); // 768 KB
    float*          pstats = (float*)(ws + 68157440ull + 1572864ull);        // 2 MB

    k_conv<<<(FF * FF / 4 + 255) / 256, 256, 0, stream>>>(W2, W2b, FF * FF / 4);
    k_gate<<<NB / 256, 256, 0, stream>>>(x, a, Wg, bg, scores);

    for (int c = 0; c < NB / CHUNK; ++c) {
        const float* xc = x + (size_t)c * CHUNK * OBS;
        const float* ac = a + (size_t)c * CHUNK * ACTD;
        const float* sc = scores + (size_t)c * CHUNK * MIX;
        float* oc = out + (size_t)c * CHUNK;
        k_prep<<<32, 256, 0, stream>>>(xc, ac, W1, b1, xabc, W1b);
        k_gemm1<<<(CHUNK / 128) * (FF / 128), 256, 0, stream>>>(xabc, W1b, h1c, pstats);
        k_ln1<<<CHUNK / 8, 256, 0, stream>>>(h1c, pstats, g1, be1);
        k_gemm2<<<(CHUNK / 128) * (FF / 256), 512, 0, stream>>>(h1c, W2b, y2c);
        k_epi<<<CHUNK, 256, 0, stream>>>(y2c, sc, b2, g2, be2, W3, b3, oc);
    }
}

// Round 15
// 717.938 us; speedup vs baseline: 1.1786x; 1.1786x over previous
//
#include <hip/hip_runtime.h>
#include <stdint.h>

#define OBS 64
#define ACTD 16
#define DIN 80          // OBS+ACT
#define MIX 16
#define FF 4096         // HID*MIX
#define NB 16384        // batch
#define CHUNK 4096      // rows per pipeline chunk
#define KP 96           // padded K for GEMM1 (80 + bias col + zeros)
#define LNEPS 1e-5f

typedef float f32x4 __attribute__((ext_vector_type(4)));
typedef short bf16x8 __attribute__((ext_vector_type(8)));

__device__ __forceinline__ unsigned short f2bf(float f) {
    union { float f; uint32_t u; } v; v.f = f;
    uint32_t u = v.u;
    u += 0x7fff + ((u >> 16) & 1);          // RNE
    return (unsigned short)(u >> 16);
}
__device__ __forceinline__ float bf2f(unsigned short h) {
    union { uint32_t u; float f; } v; v.u = ((uint32_t)h) << 16;
    return v.f;
}

// ---------------------------------------------------------------- W2 -> bf16
__global__ __launch_bounds__(256) void k_conv(const float* __restrict__ W,
                                              unsigned short* __restrict__ O, int n4) {
    int i = blockIdx.x * 256 + threadIdx.x;
    if (i >= n4) return;
    float4 v = ((const float4*)W)[i];
    ushort4 o;
    o.x = f2bf(v.x); o.y = f2bf(v.y); o.z = f2bf(v.z); o.w = f2bf(v.w);
    ((ushort4*)O)[i] = o;
}

// ------------- fused prep: blocks 0-15 -> xab rows; blocks 16-31 -> W1b rows
__global__ __launch_bounds__(256) void k_prep(const float* __restrict__ x, const float* __restrict__ a,
                                              const float* __restrict__ W1, const float* __restrict__ b1,
                                              unsigned short* __restrict__ xab,
                                              unsigned short* __restrict__ W1b) {
    int t = threadIdx.x;
    if (blockIdx.x < 16) {
        int row = blockIdx.x * 256 + t;
        const float4* xp = (const float4*)(x + (size_t)row * OBS);
        unsigned short* o = xab + (size_t)row * KP;
#pragma unroll
        for (int i = 0; i < 16; ++i) {
            float4 v = xp[i];
            ushort4 u; u.x = f2bf(v.x); u.y = f2bf(v.y); u.z = f2bf(v.z); u.w = f2bf(v.w);
            ((ushort4*)o)[i] = u;
        }
        const float4* ap = (const float4*)(a + (size_t)row * ACTD);
#pragma unroll
        for (int i = 0; i < 4; ++i) {
            float4 v = ap[i];
            ushort4 u; u.x = f2bf(v.x); u.y = f2bf(v.y); u.z = f2bf(v.z); u.w = f2bf(v.w);
            ((ushort4*)(o + OBS))[i] = u;
        }
        ushort4 t0; t0.x = 0x3F80; t0.y = 0; t0.z = 0; t0.w = 0;   // 1.0bf16
        ushort4 z;  z.x = 0; z.y = 0; z.z = 0; z.w = 0;
        ((ushort4*)(o + 80))[0] = t0;
        ((ushort4*)(o + 84))[0] = z;
        ((ushort4*)(o + 88))[0] = z;
        ((ushort4*)(o + 92))[0] = z;
    } else {
        int f = (blockIdx.x - 16) * 256 + t;
        const float4* wp = (const float4*)(W1 + (size_t)f * DIN);
        unsigned short* o = W1b + (size_t)f * KP;
#pragma unroll
        for (int i = 0; i < 20; ++i) {
            float4 v = wp[i];
            ushort4 u; u.x = f2bf(v.x); u.y = f2bf(v.y); u.z = f2bf(v.z); u.w = f2bf(v.w);
            ((ushort4*)o)[i] = u;
        }
        ushort4 t0; t0.x = f2bf(b1[f]); t0.y = 0; t0.z = 0; t0.w = 0;
        ushort4 z;  z.x = 0; z.y = 0; z.z = 0; z.w = 0;
        ((ushort4*)(o + 80))[0] = t0;
        ((ushort4*)(o + 84))[0] = z;
        ((ushort4*)(o + 88))[0] = z;
        ((ushort4*)(o + 92))[0] = z;
    }
}

// ------------------------------------------------- gating (fp64) + top4 + renorm
__global__ __launch_bounds__(256) void k_gate(const float* __restrict__ x, const float* __restrict__ a,
                                              const float* __restrict__ Wg, const float* __restrict__ bg,
                                              float* __restrict__ scores) {
    __shared__ float wgs[MIX * DIN];
    __shared__ float bgs[MIX];
    int t = threadIdx.x;
    for (int e = t; e < MIX * DIN; e += 256) wgs[e] = Wg[e];
    if (t < MIX) bgs[t] = bg[t];
    __syncthreads();
    int row = blockIdx.x * 256 + t;
    float xa[DIN];
    const float4* xp = (const float4*)(x + (size_t)row * OBS);
#pragma unroll
    for (int i = 0; i < OBS / 4; ++i) {
        float4 v = xp[i];
        xa[i*4] = v.x; xa[i*4+1] = v.y; xa[i*4+2] = v.z; xa[i*4+3] = v.w;
    }
    const float4* ap = (const float4*)(a + (size_t)row * ACTD);
#pragma unroll
    for (int i = 0; i < ACTD / 4; ++i) {
        float4 v = ap[i];
        xa[OBS+i*4] = v.x; xa[OBS+i*4+1] = v.y; xa[OBS+i*4+2] = v.z; xa[OBS+i*4+3] = v.w;
    }
    double p[MIX];
    double mx = -1e300;
#pragma unroll
    for (int m = 0; m < MIX; ++m) {
        double acc = (double)bgs[m];
#pragma unroll
        for (int k = 0; k < DIN; ++k) acc += (double)xa[k] * (double)wgs[m*DIN + k];
        p[m] = acc;
        if (acc > mx) mx = acc;
    }
#pragma unroll
    for (int m = 0; m < MIX; ++m) p[m] = exp(p[m] - mx);
    unsigned used = 0;
    double s4 = 0.0;
#pragma unroll
    for (int j = 0; j < 4; ++j) {
        int best = 0; double bv = -1.0;
#pragma unroll
        for (int m = 0; m < MIX; ++m)
            if (!((used >> m) & 1) && p[m] > bv) { bv = p[m]; best = m; }
        used |= 1u << best;
        s4 += bv;
    }
    float* so = scores + (size_t)row * MIX;
#pragma unroll
    for (int m = 0; m < MIX; ++m)
        so[m] = ((used >> m) & 1) ? (float)(p[m] / s4) : 0.f;
}

// ---------------- GEMM1 (bf16 MFMA): h1 = xab @ W1b^T, pre-LN bf16 + partial stats
// Whole 128x96 A and B tiles staged ONCE (48KB LDS), single barrier, 48 MFMAs.
__global__ __launch_bounds__(256) void k_gemm1(const unsigned short* __restrict__ A,
                                               const unsigned short* __restrict__ B,
                                               unsigned short* __restrict__ C,
                                               float* __restrict__ pstats) {
    __shared__ alignas(16) unsigned short As[12288];   // 128 x 96
    __shared__ alignas(16) unsigned short Bs[12288];
    int t = threadIdx.x;
    int pm = blockIdx.x & 31;        // 32 M tiles (CHUNK/128)
    int pn = blockIdx.x >> 5;        // 32 N tiles
    int lane = t & 63, wid = t >> 6, wm = wid >> 1, wn = wid & 1;
    int l15 = lane & 15, l4 = lane >> 4;

    const unsigned short* Ap = A + (size_t)pm * 128 * KP;
    const unsigned short* Bp = B + (size_t)pn * 128 * KP;

#pragma unroll
    for (int i = 0; i < 6; ++i) {
        int u = i * 256 + t;
        int r = u / 12, s12 = u - r * 12;
        int q = s12 >> 2, s = s12 & 3;
        int goff = r * KP + q * 32 + ((s ^ ((r >> 1) & 3)) * 8);   // pre-swizzled source
        __builtin_amdgcn_global_load_lds(
            (const __attribute__((address_space(1))) void*)(Ap + goff),
            (__attribute__((address_space(3))) void*)(As + u * 8), 16, 0, 0);
        __builtin_amdgcn_global_load_lds(
            (const __attribute__((address_space(1))) void*)(Bp + goff),
            (__attribute__((address_space(3))) void*)(Bs + u * 8), 16, 0, 0);
    }
    __syncthreads();

    f32x4 acc[4][4] = {};
#pragma unroll
    for (int q = 0; q < 3; ++q) {
        bf16x8 af[4], bfr[4];
#pragma unroll
        for (int mf = 0; mf < 4; ++mf) {
            int r = wm * 64 + mf * 16 + l15;
            int sl = l4 ^ ((r >> 1) & 3);
            af[mf] = *(const bf16x8*)(As + (r * 12 + q * 4 + sl) * 8);
        }
#pragma unroll
        for (int nf = 0; nf < 4; ++nf) {
            int r = wn * 64 + nf * 16 + l15;
            int sl = l4 ^ ((r >> 1) & 3);
            bfr[nf] = *(const bf16x8*)(Bs + (r * 12 + q * 4 + sl) * 8);
        }
#pragma unroll
        for (int mf = 0; mf < 4; ++mf)
#pragma unroll
            for (int nf = 0; nf < 4; ++nf)
                acc[mf][nf] = __builtin_amdgcn_mfma_f32_16x16x32_bf16(af[mf], bfr[nf], acc[mf][nf], 0, 0, 0);
    }

    int rowbase = pm * 128 + wm * 64 + l4 * 4;
    int colbase = pn * 128 + wn * 64 + l15;
#pragma unroll
    for (int mf = 0; mf < 4; ++mf) {
#pragma unroll
        for (int rr = 0; rr < 4; ++rr) {
            float ss = 0.f, qq = 0.f;
#pragma unroll
            for (int nf = 0; nf < 4; ++nf) {
                float v = acc[mf][nf][rr];
                ss += v; qq += v * v;
                C[(size_t)(rowbase + mf * 16 + rr) * FF + colbase + nf * 16] = f2bf(v);
            }
#pragma unroll
            for (int mask = 1; mask <= 8; mask <<= 1) {
                ss += __shfl_xor(ss, mask);
                qq += __shfl_xor(qq, mask);
            }
            if (l15 == 0) {
                int row = rowbase + mf * 16 + rr;
                int j = pn * 2 + wn;
                pstats[((size_t)row * 64 + j) * 2 + 0] = ss;
                pstats[((size_t)row * 64 + j) * 2 + 1] = qq;
            }
        }
    }
}

// ---------------- LN1 finalize: reduce 64 partials/row, normalize+ReLU h1 in place
__global__ __launch_bounds__(256) void k_ln1(unsigned short* __restrict__ h1,
                                             const float* __restrict__ pstats,
                                             const float* __restrict__ g1, const float* __restrict__ be1) {
    __shared__ float st[8][2];
    int t = threadIdx.x;
    int r0 = blockIdx.x * 8;
    if (t < 8) {
        float s = 0.f, q = 0.f;
        const float* pp = pstats + (size_t)(r0 + t) * 128;
#pragma unroll
        for (int j = 0; j < 64; ++j) { s += pp[j * 2]; q += pp[j * 2 + 1]; }
        float mu = s / (float)FF;
        float var = q / (float)FF - mu * mu;
        st[t][0] = mu;
        st[t][1] = rsqrtf(var + LNEPS);
    }
    __syncthreads();
    int c = t * 16;
    float g[16], b[16];
#pragma unroll
    for (int q = 0; q < 4; ++q) {
        float4 gv = *(const float4*)(g1 + c + q * 4);
        float4 bv = *(const float4*)(be1 + c + q * 4);
        g[q*4] = gv.x; g[q*4+1] = gv.y; g[q*4+2] = gv.z; g[q*4+3] = gv.w;
        b[q*4] = bv.x; b[q*4+1] = bv.y; b[q*4+2] = bv.z; b[q*4+3] = bv.w;
    }
    for (int r = 0; r < 8; ++r) {
        float mu = st[r][0], rs = st[r][1];
        unsigned short* hp = h1 + (size_t)(r0 + r) * FF + c;
        uint4 u0 = *(const uint4*)hp;
        uint4 u1 = *(const uint4*)(hp + 8);
        uint32_t uu[8] = {u0.x, u0.y, u0.z, u0.w, u1.x, u1.y, u1.z, u1.w};
        uint32_t oo[8];
#pragma unroll
        for (int q = 0; q < 8; ++q) {
            float v0 = bf2f((unsigned short)(uu[q] & 0xffff));
            float v1 = bf2f((unsigned short)(uu[q] >> 16));
            float o0 = fmaxf((v0 - mu) * rs * g[q*2]   + b[q*2],   0.f);
            float o1 = fmaxf((v1 - mu) * rs * g[q*2+1] + b[q*2+1], 0.f);
            oo[q] = (uint32_t)f2bf(o0) | ((uint32_t)f2bf(o1) << 16);
        }
        uint4 w0; w0.x = oo[0]; w0.y = oo[1]; w0.z = oo[2]; w0.w = oo[3];
        uint4 w1; w1.x = oo[4]; w1.y = oo[5]; w1.z = oo[6]; w1.w = oo[7];
        *(uint4*)hp = w0;
        *(uint4*)(hp + 8) = w1;
    }
}

// ------------- GEMM2: y2 = h1 @ W2^T  (bf16 MFMA, 256x256, R10/R12 schedule verbatim)
__global__ __launch_bounds__(512, 1) void k_gemm2(const unsigned short* __restrict__ A,
                                                  const unsigned short* __restrict__ B,
                                                  unsigned short* __restrict__ C) {
    constexpr int K = FF;                // 4096
    constexpr int NKT = K / 64;          // 64 K-tiles
    __shared__ alignas(16) unsigned short As[2][2][8192];   // [buf][half][128*64]
    __shared__ alignas(16) unsigned short Bs[2][2][8192];

    int t = threadIdx.x;
    int lane = t & 63, wid = t >> 6;
    int wm = wid >> 2, wn = wid & 3;     // 2 x 4 waves

    // bijective XCD-rectangle block swizzle: 16x16 tile grid, 256 blocks
    int bid = blockIdx.x;
    int xcd = bid & 7, w = bid >> 3;
    int pm = (xcd >> 1) * 4 + (w >> 3);
    int pn = (xcd & 1) * 8 + (w & 7);

    const unsigned short* Ap = A + (size_t)pm * 256 * K;
    const unsigned short* Bp = B + (size_t)pn * 256 * K;

    // ---- hoisted LDS read bases (byte offsets; all per-tile deltas are compile-time) ----
    int l15 = lane & 15, l4 = lane >> 4;
    int slk0 = (l4 ^ (l15 & 7)) * 16;          // kk=0 swizzle slot (row deltas all ≡0 mod 8)
    int slk1 = ((4 + l4) ^ (l15 & 7)) * 16;    // kk=1
    const char* Abase = (const char*)&As[0][0][0];
    const char* Bbase = (const char*)&Bs[0][0][0];
    const char* afp0 = Abase + wm * 16384 + l15 * 128 + slk0;
    const char* afp1 = Abase + wm * 16384 + l15 * 128 + slk1;
    const char* bfp0 = Bbase + (wn >> 1) * 16384 + (wn & 1) * 8192 + l15 * 128 + slk0;
    const char* bfp1 = Bbase + (wn >> 1) * 16384 + (wn & 1) * 8192 + l15 * 128 + slk1;

    // ---- hoisted staging pointers (positioned at K-tile 0; advance +64 elems per tile) ----
    int r0 = t >> 3;
    int swz = ((t & 7) ^ (r0 & 7)) * 8;        // constant across all 8 variants (row deltas ≡0 mod 8)
    const unsigned short* sA0 = Ap + (size_t)(r0)       * K + swz;
    const unsigned short* sA1 = Ap + (size_t)(64 + r0)  * K + swz;
    const unsigned short* sA2 = Ap + (size_t)(128 + r0) * K + swz;
    const unsigned short* sA3 = Ap + (size_t)(192 + r0) * K + swz;
    const unsigned short* sB0 = Bp + (size_t)(r0)       * K + swz;
    const unsigned short* sB1 = Bp + (size_t)(64 + r0)  * K + swz;
    const unsigned short* sB2 = Bp + (size_t)(128 + r0) * K + swz;
    const unsigned short* sB3 = Bp + (size_t)(192 + r0) * K + swz;
    char* dA = (char*)&As[0][0][0] + t * 16;   // linear LDS dest base
    char* dB = (char*)&Bs[0][0][0] + t * 16;

    f32x4 acc[8][4] = {};
    bf16x8 af[4][2], bfr[4][2];

#define STG_A(BUF, HH, p0, p1)                                                              \
    __builtin_amdgcn_global_load_lds((const __attribute__((address_space(1))) void*)(p0),   \
        (__attribute__((address_space(3))) void*)(dA + (BUF)*32768 + (HH)*16384), 16, 0, 0);\
    __builtin_amdgcn_global_load_lds((const __attribute__((address_space(1))) void*)(p1),   \
        (__attribute__((address_space(3))) void*)(dA + (BUF)*32768 + (HH)*16384 + 8192), 16, 0, 0);
#define STG_B(BUF, HH, p0, p1)                                                              \
    __builtin_amdgcn_global_load_lds((const __attribute__((address_space(1))) void*)(p0),   \
        (__attribute__((address_space(3))) void*)(dB + (BUF)*32768 + (HH)*16384), 16, 0, 0);\
    __builtin_amdgcn_global_load_lds((const __attribute__((address_space(1))) void*)(p1),   \
        (__attribute__((address_space(3))) void*)(dB + (BUF)*32768 + (HH)*16384 + 8192), 16, 0, 0);

#define RD_AF(BUF, MH)                                                                      \
    _Pragma("unroll") for (int m = 0; m < 4; ++m) {                                         \
        af[m][0] = *(const bf16x8*)(afp0 + (BUF)*32768 + (MH)*8192 + m*2048);               \
        af[m][1] = *(const bf16x8*)(afp1 + (BUF)*32768 + (MH)*8192 + m*2048);               \
    }
#define RD_BF(BUF)                                                                          \
    _Pragma("unroll") for (int n2 = 0; n2 < 4; ++n2) {                                      \
        bfr[n2][0] = *(const bf16x8*)(bfp0 + (BUF)*32768 + n2*2048);                        \
        bfr[n2][1] = *(const bf16x8*)(bfp1 + (BUF)*32768 + n2*2048);                        \
    }

#define MFMA_Q(MB, NLO)                                                                     \
    __builtin_amdgcn_s_setprio(1);                                                          \
    _Pragma("unroll") for (int kk = 0; kk < 2; ++kk)                                        \
    _Pragma("unroll") for (int m = 0; m < 4; ++m)                                           \
    _Pragma("unroll") for (int n = (NLO); n < (NLO) + 2; ++n)                               \
        acc[(MB)*4 + m][n] = __builtin_amdgcn_mfma_f32_16x16x32_bf16(                       \
            af[m][kk], bfr[n][kk], acc[(MB)*4 + m][n], 0, 0, 0);                            \
    __builtin_amdgcn_s_setprio(0);                                                          \
    __builtin_amdgcn_sched_barrier(0);

    // TILE: R10's exact phase/sync layout. Stages target buf BUF^1 (next K-tile).
#define TILE(BUF, DO_STAGE)                                                                 \
    if (DO_STAGE) { STG_A(1 - (BUF), 0, sA0, sA1) }                                         \
    if (DO_STAGE) asm volatile("s_waitcnt vmcnt(2)" ::: "memory");                          \
    else          asm volatile("s_waitcnt vmcnt(0)" ::: "memory");                          \
    __builtin_amdgcn_s_barrier();                                                           \
    __builtin_amdgcn_sched_barrier(0);                                                      \
    RD_AF(BUF, 0) RD_BF(BUF)                                                                \
    MFMA_Q(0, 0)                                                                            \
    if (DO_STAGE) { STG_A(1 - (BUF), 1, sA2, sA3) }                                         \
    MFMA_Q(0, 2)                                                                            \
    if (DO_STAGE) { STG_B(1 - (BUF), 0, sB0, sB1) }                                         \
    RD_AF(BUF, 1)                                                                           \
    MFMA_Q(1, 0)                                                                            \
    if (DO_STAGE) { STG_B(1 - (BUF), 1, sB2, sB3) }                                         \
    MFMA_Q(1, 2)                                                                            \
    asm volatile("" ::: "memory");                                                          \
    __builtin_amdgcn_s_barrier();                                                           \
    asm volatile("" ::: "memory");                                                          \
    if (DO_STAGE) { sA0 += 64; sA1 += 64; sA2 += 64; sA3 += 64;                             \
                    sB0 += 64; sB1 += 64; sB2 += 64; sB3 += 64; }

    // prologue: stage all 4 halves of K-tile 0 into buf0; advance pointers to tile 1
    STG_A(0, 0, sA0, sA1) STG_A(0, 1, sA2, sA3)
    STG_B(0, 0, sB0, sB1) STG_B(0, 1, sB2, sB3)
    sA0 += 64; sA1 += 64; sA2 += 64; sA3 += 64;
    sB0 += 64; sB1 += 64; sB2 += 64; sB3 += 64;
    asm volatile("" ::: "memory");

    for (int i = 0; i < NKT / 2 - 1; ++i) {
        TILE(0, true)
        TILE(1, true)
    }
    TILE(0, true)       // tile 62 (stages tile 63)
    TILE(1, false)      // tile 63 (no stages; vmcnt(0))

#undef STG_A
#undef STG_B
#undef RD_AF
#undef RD_BF
#undef MFMA_Q
#undef TILE

    int row0 = pm * 256 + wm * 128 + (lane >> 4) * 4;
    int col0 = pn * 256 + wn * 64 + (lane & 15);
#pragma unroll
    for (int gm = 0; gm < 8; ++gm)
#pragma unroll
        for (int gn = 0; gn < 4; ++gn)
#pragma unroll
            for (int rr = 0; rr < 4; ++rr)
                C[(size_t)(row0 + gm * 16 + rr) * FF + col0 + gn * 16] = f2bf(acc[gm][gn][rr]);
}

// ------------------- fused +b2, LN2, ReLU, score mixture, x W3 + b3 -> out[row]
__global__ __launch_bounds__(256) void k_epi(const unsigned short* __restrict__ y2,
                                             const float* __restrict__ scores,
                                             const float* __restrict__ b2,
                                             const float* __restrict__ g2, const float* __restrict__ be2,
                                             const float* __restrict__ W3, const float* __restrict__ b3,
                                             float* __restrict__ out) {
    int row = blockIdx.x, t = threadIdx.x;
    int lane = t & 63, wid = t >> 6;
    __shared__ float sS[MIX];
    __shared__ float rA[4], rB[4];
    __shared__ float stats[2];
    const unsigned short* yp = y2 + (size_t)row * FF + t * 16;
    uint4 u0 = *(const uint4*)yp;
    uint4 u1 = *(const uint4*)(yp + 8);
    float v[16];
    v[0]  = bf2f((unsigned short)(u0.x & 0xffff)); v[1]  = bf2f((unsigned short)(u0.x >> 16));
    v[2]  = bf2f((unsigned short)(u0.y & 0xffff)); v[3]  = bf2f((unsigned short)(u0.y >> 16));
    v[4]  = bf2f((unsigned short)(u0.z & 0xffff)); v[5]  = bf2f((unsigned short)(u0.z >> 16));
    v[6]  = bf2f((unsigned short)(u0.w & 0xffff)); v[7]  = bf2f((unsigned short)(u0.w >> 16));
    v[8]  = bf2f((unsigned short)(u1.x & 0xffff)); v[9]  = bf2f((unsigned short)(u1.x >> 16));
    v[10] = bf2f((unsigned short)(u1.y & 0xffff)); v[11] = bf2f((unsigned short)(u1.y >> 16));
    v[12] = bf2f((unsigned short)(u1.z & 0xffff)); v[13] = bf2f((unsigned short)(u1.z >> 16));
    v[14] = bf2f((unsigned short)(u1.w & 0xffff)); v[15] = bf2f((unsigned short)(u1.w >> 16));
    const float* b2p = b2 + t * 16;
#pragma unroll
    for (int blk = 0; blk < 4; ++blk) {
        float4 q = *(const float4*)(b2p + blk * 4);
        v[blk*4+0] += q.x; v[blk*4+1] += q.y; v[blk*4+2] += q.z; v[blk*4+3] += q.w;
    }
    if (t < MIX) sS[t] = scores[(size_t)row * MIX + t];
    float s = 0.f, sq = 0.f;
#pragma unroll
    for (int j = 0; j < 16; ++j) { s += v[j]; sq += v[j] * v[j]; }
#pragma unroll
    for (int off = 32; off >= 1; off >>= 1) {
        s  += __shfl_down(s, off);
        sq += __shfl_down(sq, off);
    }
    if (lane == 0) { rA[wid] = s; rB[wid] = sq; }
    __syncthreads();
    if (t == 0) {
        float S = rA[0] + rA[1] + rA[2] + rA[3];
        float Q = rB[0] + rB[1] + rB[2] + rB[3];
        float mu = S / (float)FF;
        float var = Q / (float)FF - mu * mu;
        stats[0] = mu;
        stats[1] = rsqrtf(var + LNEPS);
    }
    __syncthreads();
    float mu = stats[0], rs = stats[1];
    const float* gp = g2 + t * 16;
    const float* bp = be2 + t * 16;
    float accum = 0.f;
#pragma unroll
    for (int blk = 0; blk < 4; ++blk) {
        float4 gg = *(const float4*)(gp + blk * 4);
        float4 bb = *(const float4*)(bp + blk * 4);
        float ga[4] = {gg.x, gg.y, gg.z, gg.w};
        float ba[4] = {bb.x, bb.y, bb.z, bb.w};
#pragma unroll
        for (int jj = 0; jj < 4; ++jj) {
            int m = blk * 4 + jj;
            float o = (v[m] - mu) * rs * ga[jj] + ba[jj];
            o = fmaxf(o, 0.f);
            accum += o * sS[m];
        }
    }
    float part = accum * W3[t] * 0.0625f;   // /16 (mean over MIX)
#pragma unroll
    for (int off = 32; off >= 1; off >>= 1) part += __shfl_down(part, off);
    if (lane == 0) rA[wid] = part;
    __syncthreads();
    if (t == 0) out[row] = rA[0] + rA[1] + rA[2] + rA[3] + b3[0];
}

extern "C" void kernel_launch(void* const* d_in, const int* in_sizes, int n_in,
                              void* d_out, int out_size, void* d_ws, size_t ws_size,
                              hipStream_t stream) {
    const float* x   = (const float*)d_in[0];
    const float* a   = (const float*)d_in[1];
    const float* W1  = (const float*)d_in[2];
    const float* b1  = (const float*)d_in[3];
    const float* W2  = (const float*)d_in[4];
    const float* b2  = (const float*)d_in[5];
    const float* W3  = (const float*)d_in[6];
    const float* b3  = (const float*)d_in[7];
    const float* g1  = (const float*)d_in[8];
    const float* be1 = (const float*)d_in[9];
    const float* g2  = (const float*)d_in[10];
    const float* be2 = (const float*)d_in[11];
    const float* Wg  = (const float*)d_in[12];
    const float* bg  = (const float*)d_in[13];
    float* out = (float*)d_out;

    // workspace layout — total 101,711,872 B (R2-proven-safe footprint).
    char* ws = (char*)d_ws;
    unsigned short* W2b    = (unsigned short*)ws;                    // 32 MB
    float*          scores = (float*)(ws + 33554432ull);            // 1 MB
    unsigned short* h1c    = (unsigned short*)(ws + 34603008ull);    // 32 MB
    unsigned short* y2c    = (unsigned short*)(ws + 68157440ull);    // 32 MB (+scratch head)
    unsigned short* xabc   = (unsigned short*)(ws + 68157440ull);            // 768 KB
    unsigned short* W1b    = (unsigned short*)(ws + 68157440ull + 786432ull); // 768 KB
    float*          pstats = (float*)(ws + 68157440ull + 1572864ull);        // 2 MB

    k_conv<<<(FF * FF / 4 + 255) / 256, 256, 0, stream>>>(W2, W2b, FF * FF / 4);
    k_gate<<<NB / 256, 256, 0, stream>>>(x, a, Wg, bg, scores);

    for (int c = 0; c < NB / CHUNK; ++c) {
        const float* xc = x + (size_t)c * CHUNK * OBS;
        const float* ac = a + (size_t)c * CHUNK * ACTD;
        const float* sc = scores + (size_t)c * CHUNK * MIX;
        float* oc = out + (size_t)c * CHUNK;
        k_prep<<<32, 256, 0, stream>>>(xc, ac, W1, b1, xabc, W1b);
        k_gemm1<<<(CHUNK / 128) * (FF / 128), 256, 0, stream>>>(xabc, W1b, h1c, pstats);
        k_ln1<<<CHUNK / 8, 256, 0, stream>>>(h1c, pstats, g1, be1);
        k_gemm2<<<(CHUNK / 256) * (FF / 256), 512, 0, stream>>>(h1c, W2b, y2c);
        k_epi<<<CHUNK, 256, 0, stream>>>(y2c, sc, b2, g2, be2, W3, b3, oc);
    }
}